// Round 9
// baseline (433.028 us; speedup 1.0000x reference)
//
#include <hip/hip_runtime.h>
#include <hip/hip_bf16.h>
#include <math.h>

#define T_DIM 2048
#define K_DIM 17
#define HID   64
#define B_DIM 32

typedef short s16x8 __attribute__((ext_vector_type(8)));
typedef short s16x4 __attribute__((ext_vector_type(4)));
typedef unsigned u32x2 __attribute__((ext_vector_type(2)));
typedef float f32x4 __attribute__((ext_vector_type(4)));

__device__ __forceinline__ float bf2f(short u) {
    unsigned v = ((unsigned)(unsigned short)u) << 16;
    return __builtin_bit_cast(float, v);
}
__device__ __forceinline__ short f2bf(float f) {          // cold path
    __hip_bfloat16 h = __float2bfloat16(f);
    return __builtin_bit_cast(short, h);
}
__device__ __forceinline__ short f2bf_fast(float f) {
    unsigned u = __builtin_bit_cast(unsigned, f);
    return (short)((u + 0x8000u) >> 16);
}
__device__ __forceinline__ unsigned pk2bf(float lo, float hi) {
    unsigned ul = __builtin_bit_cast(unsigned, lo);
    unsigned uh = __builtin_bit_cast(unsigned, hi);
    return ((ul + 0x8000u) >> 16) | ((uh + 0x8000u) & 0xFFFF0000u);
}

// COCO skeleton sparsity: column-v nonzeros of adj (incl. self).
static constexpr int NBR_PTR[18] = {0,3,6,9,11,13,17,21,24,27,29,31,34,37,40,43,45,47};
static constexpr int NBR_K[47] = {
    0,1,2,  0,1,3,  0,2,4,  1,3,  2,4,
    5,6,7,11,  5,6,8,12,  5,7,9,  6,8,10,  7,9,  8,10,
    5,11,13,  6,12,14,  11,13,15,  12,14,16,  13,15,  14,16 };

// ---------------------------------------------------------------------------
// Fold GCN channel-mix into temporal conv weights (bf16).
//   effT0[o][k32]  k = dt*8+cin (cin<3, dt<3), rest 0    (block1, K=32)
//   effT12[blk][o][dt*64+c]                              (blocks 2,3, K=192)
//   bnc[blk*64+o] = s/sqrt(v+eps);  bnc[192+blk*64+o] = b - m*inv
// ---------------------------------------------------------------------------
__global__ void fold_weights_kernel(
    const float* __restrict__ gw0, const float* __restrict__ gw1,
    const float* __restrict__ gw2, const float* __restrict__ tcn,
    const float* __restrict__ bns, const float* __restrict__ bnb,
    const float* __restrict__ bnm, const float* __restrict__ bnv,
    short* __restrict__ effT0, short* __restrict__ effT12,
    float* __restrict__ bnc)
{
    int tid = blockIdx.x * blockDim.x + threadIdx.x;
    int stride = gridDim.x * blockDim.x;
    for (int idx = tid; idx < 2048; idx += stride) {
        int o = idx >> 5, k = idx & 31, dt = k >> 3, cin = k & 7;
        float s = 0.f;
        if (dt < 3 && cin < 3)
            for (int m = 0; m < 64; m++)
                s += gw0[cin * 64 + m] * tcn[(o * 64 + m) * 3 + dt];
        effT0[idx] = f2bf(s);
    }
    for (int idx = tid; idx < 24576; idx += stride) {
        int blk = idx / 12288;
        int r = idx - blk * 12288;
        int o = r / 192, k = r - o * 192, dt = k >> 6, c = k & 63;
        const float* gw = blk ? gw2 : gw1;
        const float* tw = tcn + (size_t)(blk + 1) * 64 * 64 * 3;
        float s = 0.f;
        for (int m = 0; m < 64; m++)
            s += gw[c * 64 + m] * tw[(o * 64 + m) * 3 + dt];
        effT12[idx] = f2bf(s);
    }
    for (int i = tid; i < 192; i += stride) {
        float inv = bns[i] * rsqrtf(bnv[i] + 1e-5f);
        bnc[i] = inv;
        bnc[192 + i] = bnb[i] - bnm[i] * inv;
    }
}

// ---------------------------------------------------------------------------
// Adjacency-last structure (graph-mix commutes with the (dt,c) contraction):
//   z[t,k,o] = conv_W(y)[t,k,o]  (GEMM, B-frags straight from raw input)
//   out[t,v,o] = BN(Σ_k adj[k,v] z[t,k,o]) -> ReLU -> +residual
//
// Kernel 1: block1. TT=8. x tile (10 t x 51 f) in LDS; GEMM1 B-fragment is
// gathered per-lane from xt (3 floats, dt=kgrp); z -> LDS; mix -> y1 global.
// ---------------------------------------------------------------------------
__global__ __launch_bounds__(256, 5) void stgcn_b1_kernel(
    const float* __restrict__ x, const float* __restrict__ adj,
    const short* __restrict__ effT0, const float* __restrict__ bnc,
    short* __restrict__ y1)
{
    __shared__ float adj_s[289];
    __shared__ __align__(16) float xt[10 * 51];     // 2040 B
    __shared__ __align__(16) short z[136 * 72];     // 19584 B

    const int tid = threadIdx.x;
    const int b = blockIdx.y;
    const int t0 = blockIdx.x * 8;
    const int lane = tid & 63, wave = tid >> 6;
    const int col = lane & 15, kgrp = lane >> 4;

    for (int i = tid; i < 289; i += 256) adj_s[i] = adj[i];
    {
        const int tbase = t0 - 1;
        const float* xb = x + (size_t)(b * T_DIM + tbase) * 51;
        for (int i = tid; i < 510; i += 256) {
            int tt = tbase + i / 51;
            xt[i] = (tt >= 0 && tt < T_DIM) ? xb[i] : 0.f;
        }
    }
    s16x8 af1[4];
    #pragma unroll
    for (int mt = 0; mt < 4; mt++)
        af1[mt] = *(const s16x8*)(effT0 + (mt * 16 + col) * 32 + kgrp * 8);
    __syncthreads();

    // GEMM1: rows 136 (9 tiles), K=32; B gathered from xt
    for (int tile = wave; tile < 9; tile += 4) {
        const int r = tile * 16 + col;
        const int me = r < 136 ? r : 135;
        const int s = (me * 241) >> 12;        // me/17 for me<256
        const int k = me - s * 17;
        s16x8 bfr = (s16x8){0,0,0,0,0,0,0,0};
        if (kgrp < 3) {                        // dt = kgrp
            const float* xp = &xt[(s + kgrp) * 51 + k * 3];
            bfr[0] = f2bf_fast(xp[0]);
            bfr[1] = f2bf_fast(xp[1]);
            bfr[2] = f2bf_fast(xp[2]);
        }
        f32x4 acc[4];
        #pragma unroll
        for (int mt = 0; mt < 4; mt++)
            acc[mt] = __builtin_amdgcn_mfma_f32_16x16x32_bf16(
                af1[mt], bfr, (f32x4){0.f, 0.f, 0.f, 0.f}, 0, 0, 0);
        if (r < 136) {
            #pragma unroll
            for (int mt = 0; mt < 4; mt++) {
                u32x2 st;
                st[0] = pk2bf(acc[mt][0], acc[mt][1]);
                st[1] = pk2bf(acc[mt][2], acc[mt][3]);
                *(u32x2*)&z[r * 72 + mt * 16 + kgrp * 4] = st;
            }
        }
    }
    __syncthreads();

    // mix: thread = (tl, o-pair); out[t,v,o] = relu(bn(sum_k adj*z))
    const int tl = tid >> 5, oq = tid & 31, o0 = oq * 2;
    const float inv0 = bnc[o0], inv1 = bnc[o0 + 1];
    const float sh0 = bnc[192 + o0], sh1 = bnc[192 + o0 + 1];
    float zk0[17], zk1[17];
    #pragma unroll
    for (int k = 0; k < 17; k++) {
        unsigned u = *(const unsigned*)&z[(tl * 17 + k) * 72 + o0];
        zk0[k] = bf2f((short)(u & 0xFFFF));
        zk1[k] = bf2f((short)(u >> 16));
    }
    const size_t gout = ((size_t)(b * T_DIM + t0 + tl) * K_DIM) * 64;
    #pragma unroll
    for (int v = 0; v < 17; v++) {
        float g0 = 0.f, g1 = 0.f;
        #pragma unroll
        for (int e = NBR_PTR[v]; e < NBR_PTR[v + 1]; e++) {
            int k = NBR_K[e];
            float w = adj_s[k * 17 + v];
            g0 += w * zk0[k]; g1 += w * zk1[k];
        }
        float v0 = fmaxf(g0 * inv0 + sh0, 0.f);
        float v1 = fmaxf(g1 * inv1 + sh1, 0.f);
        *(unsigned*)&y1[gout + (size_t)v * 64 + o0] = pk2bf(v0, v1);
    }
}

// ---------------------------------------------------------------------------
// Kernels 2/3: GEMM with B-fragments read DIRECTLY from yin (global, L3-hot,
// OOB rows zeroed by linear row-index compare); z -> LDS; one barrier;
// mix + BN + ReLU + residual(global), store yout or pool -> part.
// ---------------------------------------------------------------------------
template<int DIL, bool POOL>
__global__ __launch_bounds__(256, 5) void stgcn_b23_kernel(
    const short* __restrict__ yin, const float* __restrict__ adj,
    const short* __restrict__ effW, const float* __restrict__ bnc, int blk,
    short* __restrict__ yout, float* __restrict__ part, int b0)
{
    __shared__ float adj_s[289];
    __shared__ __align__(16) short z[136 * 72];     // 19584 B
    __shared__ float pr[8][64];                     // 2048 B (pool)

    const int tid = threadIdx.x;
    const int b = blockIdx.y;
    const int t0 = blockIdx.x * 8;
    const int lane = tid & 63, wave = tid >> 6;
    const int col = lane & 15, kgrp = lane >> 4;
    const int h = wave & 1;                         // o-half

    for (int i = tid; i < 289; i += 256) adj_s[i] = adj[i];

    // o-halved weight fragments (48 VGPR)
    s16x8 af[6][2];
    #pragma unroll
    for (int kk = 0; kk < 6; kk++)
        #pragma unroll
        for (int m = 0; m < 2; m++)
            af[kk][m] = *(const s16x8*)(effW +
                (h * 32 + m * 16 + col) * 192 + kk * 32 + kgrp * 8);

    // GEMM: rows 136 (9 tiles), K=192; B straight from global
    const int bLo = b * (T_DIM * 17);
    const int bHi = bLo + T_DIM * 17;
    const int grow0 = bLo + (t0 - DIL) * 17;
    for (int tile = (wave >> 1); tile < 9; tile += 2) {
        const int r = tile * 16 + col;
        const int me = r < 136 ? r : 135;
        f32x4 acc[2];
        acc[0] = (f32x4){0.f, 0.f, 0.f, 0.f};
        acc[1] = (f32x4){0.f, 0.f, 0.f, 0.f};
        #pragma unroll
        for (int kk = 0; kk < 6; kk++) {
            const int gr = grow0 + me + 17 * DIL * (kk >> 1);
            const bool ok = (gr >= bLo) & (gr < bHi);
            const short* p = yin + (size_t)(ok ? gr : bLo) * 64
                           + (kk & 1) * 32 + kgrp * 8;
            s16x8 bfr = *(const s16x8*)p;
            if (!ok) bfr = (s16x8){0,0,0,0,0,0,0,0};
            #pragma unroll
            for (int m = 0; m < 2; m++)
                acc[m] = __builtin_amdgcn_mfma_f32_16x16x32_bf16(
                    af[kk][m], bfr, acc[m], 0, 0, 0);
        }
        if (r < 136) {
            #pragma unroll
            for (int m = 0; m < 2; m++) {
                u32x2 st;
                st[0] = pk2bf(acc[m][0], acc[m][1]);
                st[1] = pk2bf(acc[m][2], acc[m][3]);
                *(u32x2*)&z[r * 72 + h * 32 + m * 16 + kgrp * 4] = st;
            }
        }
    }
    __syncthreads();

    // mix: thread = (tl, o-pair)
    const int tl = tid >> 5, oq = tid & 31, o0 = oq * 2;
    const float inv0 = bnc[blk * 64 + o0], inv1 = bnc[blk * 64 + o0 + 1];
    const float sh0 = bnc[192 + blk * 64 + o0], sh1 = bnc[192 + blk * 64 + o0 + 1];
    float zk0[17], zk1[17];
    #pragma unroll
    for (int k = 0; k < 17; k++) {
        unsigned u = *(const unsigned*)&z[(tl * 17 + k) * 72 + o0];
        zk0[k] = bf2f((short)(u & 0xFFFF));
        zk1[k] = bf2f((short)(u >> 16));
    }
    float ps0 = 0.f, ps1 = 0.f;
    const size_t gout = ((size_t)(b * T_DIM + t0 + tl) * K_DIM) * 64;
    #pragma unroll
    for (int v = 0; v < 17; v++) {
        float g0 = 0.f, g1 = 0.f;
        #pragma unroll
        for (int e = NBR_PTR[v]; e < NBR_PTR[v + 1]; e++) {
            int k = NBR_K[e];
            float w = adj_s[k * 17 + v];
            g0 += w * zk0[k]; g1 += w * zk1[k];
        }
        unsigned ru = *(const unsigned*)&yin[gout + (size_t)v * 64 + o0];
        float v0 = fmaxf(g0 * inv0 + sh0, 0.f) + bf2f((short)(ru & 0xFFFF));
        float v1 = fmaxf(g1 * inv1 + sh1, 0.f) + bf2f((short)(ru >> 16));
        if (POOL) { ps0 += v0; ps1 += v1; }
        else *(unsigned*)&yout[gout + (size_t)v * 64 + o0] = pk2bf(v0, v1);
    }
    if (POOL) {
        *(float2*)&pr[tl][o0] = make_float2(ps0, ps1);
        __syncthreads();
        if (tid < 64) {
            float s = 0.f;
            #pragma unroll
            for (int i = 0; i < 8; i++) s += pr[i][tid];
            part[((size_t)(b0 + b) * 256 + blockIdx.x) * 64 + tid] = s;
        }
    }
}

// ---------------------------------------------------------------------------
// Sum 256 partials per (b,c), mean, LayerNorm, FC. 1 wave per b.
// ---------------------------------------------------------------------------
__global__ __launch_bounds__(64) void finish_kernel(
    const float* __restrict__ part, const float* __restrict__ ln_s,
    const float* __restrict__ ln_b, const float* __restrict__ fc_w,
    const float* __restrict__ fc_b, float* __restrict__ out)
{
    const int b = blockIdx.x;
    const int c = threadIdx.x;
    float s = 0.f;
    for (int i = 0; i < 256; i++)
        s += part[((size_t)b * 256 + i) * 64 + c];
    float feat = s / (float)(T_DIM * K_DIM);

    float m = feat;
    #pragma unroll
    for (int off = 32; off > 0; off >>= 1) m += __shfl_down(m, off);
    m = __shfl(m, 0) / 64.f;
    float d = feat - m;
    float v = d * d;
    #pragma unroll
    for (int off = 32; off > 0; off >>= 1) v += __shfl_down(v, off);
    v = __shfl(v, 0) / 64.f;
    float norm = d * rsqrtf(v + 1e-5f) * ln_s[c] + ln_b[c];

    __shared__ float ns[64];
    ns[c] = norm;
    __syncthreads();
    if (c < 10) {
        float o = fc_b[c];
        for (int i = 0; i < 64; i++) o += ns[i] * fc_w[i * 10 + c];
        out[b * 10 + c] = o;
    }
}

// ---------------------------------------------------------------------------
extern "C" void kernel_launch(void* const* d_in, const int* in_sizes, int n_in,
                              void* d_out, int out_size, void* d_ws, size_t ws_size,
                              hipStream_t stream)
{
    const float* kpts = (const float*)d_in[0];
    const float* adj  = (const float*)d_in[1];
    const float* gw0  = (const float*)d_in[2];
    const float* gw1  = (const float*)d_in[3];
    const float* gw2  = (const float*)d_in[4];
    const float* tcn  = (const float*)d_in[5];
    const float* bns  = (const float*)d_in[6];
    const float* bnb  = (const float*)d_in[7];
    const float* bnm  = (const float*)d_in[8];
    const float* bnv  = (const float*)d_in[9];
    const float* lns  = (const float*)d_in[10];
    const float* lnb  = (const float*)d_in[11];
    const float* fcw  = (const float*)d_in[12];
    const float* fcb  = (const float*)d_in[13];
    float* out = (float*)d_out;

    // ws: bnc(384 f) | part(32*256*64 f) | effT0(2048 s) | effT12(24576 s) | y1 | y2
    float* bnc  = (float*)d_ws;
    float* part = bnc + 384;
    short* effT0  = (short*)(part + (size_t)B_DIM * 256 * 64);
    short* effT12 = effT0 + 2048;
    short* y1     = effT12 + 24576;
    const size_t fixed_bytes = 384 * 4 + (size_t)B_DIM * 256 * 64 * 4
                             + 2048 * 2 + 24576 * 2;          // ~2.15 MB
    const size_t y_per_b = (size_t)T_DIM * K_DIM * 64 * 2;    // 4,456,448 B

    int cb = B_DIM;
    while (cb > 1 && fixed_bytes + 2 * (size_t)cb * y_per_b > ws_size) cb >>= 1;
    short* y2 = y1 + (size_t)cb * T_DIM * K_DIM * 64;

    fold_weights_kernel<<<64, 256, 0, stream>>>(gw0, gw1, gw2, tcn,
                                                bns, bnb, bnm, bnv,
                                                effT0, effT12, bnc);

    for (int b0 = 0; b0 < B_DIM; b0 += cb) {
        stgcn_b1_kernel<<<dim3(T_DIM / 8, cb), 256, 0, stream>>>(
            kpts + (size_t)b0 * T_DIM * K_DIM * 3, adj, effT0, bnc, y1);
        stgcn_b23_kernel<1, false><<<dim3(T_DIM / 8, cb), 256, 0, stream>>>(
            y1, adj, effT12, bnc, 1, y2, nullptr, 0);
        stgcn_b23_kernel<2, true><<<dim3(T_DIM / 8, cb), 256, 0, stream>>>(
            y2, adj, effT12 + 12288, bnc, 2, nullptr, part, b0);
    }

    finish_kernel<<<B_DIM, 64, 0, stream>>>(part, lns, lnb, fcw, fcb, out);
}

// Round 10
// 256.945 us; speedup vs baseline: 1.6853x; 1.6853x over previous
//
#include <hip/hip_runtime.h>
#include <hip/hip_bf16.h>
#include <math.h>

#define T_DIM 2048
#define K_DIM 17
#define HID   64
#define B_DIM 32

typedef short s16x8 __attribute__((ext_vector_type(8)));
typedef unsigned u32x2 __attribute__((ext_vector_type(2)));
typedef float f32x4 __attribute__((ext_vector_type(4)));

__device__ __forceinline__ float bf2f(short u) {
    unsigned v = ((unsigned)(unsigned short)u) << 16;
    return __builtin_bit_cast(float, v);
}
__device__ __forceinline__ short f2bf(float f) {          // cold path
    __hip_bfloat16 h = __float2bfloat16(f);
    return __builtin_bit_cast(short, h);
}
__device__ __forceinline__ short f2bf_fast(float f) {
    unsigned u = __builtin_bit_cast(unsigned, f);
    return (short)((u + 0x8000u) >> 16);
}
__device__ __forceinline__ unsigned pk2bf(float lo, float hi) {
    unsigned ul = __builtin_bit_cast(unsigned, lo);
    unsigned uh = __builtin_bit_cast(unsigned, hi);
    return ((ul + 0x8000u) >> 16) | ((uh + 0x8000u) & 0xFFFF0000u);
}

// COCO skeleton sparsity: column-v nonzeros of adj (incl. self).
static constexpr int NBR_PTR[18] = {0,3,6,9,11,13,17,21,24,27,29,31,34,37,40,43,45,47};
static constexpr int NBR_K[47] = {
    0,1,2,  0,1,3,  0,2,4,  1,3,  2,4,
    5,6,7,11,  5,6,8,12,  5,7,9,  6,8,10,  7,9,  8,10,
    5,11,13,  6,12,14,  11,13,15,  12,14,16,  13,15,  14,16 };

// ---------------------------------------------------------------------------
// Fold GCN channel-mix into temporal conv weights (bf16).
//   effT0[o][k32]  k = dt*8+cin (cin<3, dt<3), rest 0    (block1, K=32)
//   effT12[blk][o][dt*64+c]                              (blocks 2,3, K=192)
//   bnc[blk*64+o] = s/sqrt(v+eps);  bnc[192+blk*64+o] = b - m*inv
// ---------------------------------------------------------------------------
__global__ void fold_weights_kernel(
    const float* __restrict__ gw0, const float* __restrict__ gw1,
    const float* __restrict__ gw2, const float* __restrict__ tcn,
    const float* __restrict__ bns, const float* __restrict__ bnb,
    const float* __restrict__ bnm, const float* __restrict__ bnv,
    short* __restrict__ effT0, short* __restrict__ effT12,
    float* __restrict__ bnc)
{
    int tid = blockIdx.x * blockDim.x + threadIdx.x;
    int stride = gridDim.x * blockDim.x;
    for (int idx = tid; idx < 2048; idx += stride) {
        int o = idx >> 5, k = idx & 31, dt = k >> 3, cin = k & 7;
        float s = 0.f;
        if (dt < 3 && cin < 3)
            for (int m = 0; m < 64; m++)
                s += gw0[cin * 64 + m] * tcn[(o * 64 + m) * 3 + dt];
        effT0[idx] = f2bf(s);
    }
    for (int idx = tid; idx < 24576; idx += stride) {
        int blk = idx / 12288;
        int r = idx - blk * 12288;
        int o = r / 192, k = r - o * 192, dt = k >> 6, c = k & 63;
        const float* gw = blk ? gw2 : gw1;
        const float* tw = tcn + (size_t)(blk + 1) * 64 * 64 * 3;
        float s = 0.f;
        for (int m = 0; m < 64; m++)
            s += gw[c * 64 + m] * tw[(o * 64 + m) * 3 + dt];
        effT12[idx] = f2bf(s);
    }
    for (int i = tid; i < 192; i += stride) {
        float inv = bns[i] * rsqrtf(bnv[i] + 1e-5f);
        bnc[i] = inv;
        bnc[192 + i] = bnb[i] - bnm[i] * inv;
    }
}

// ---------------------------------------------------------------------------
// Kernel A: blocks 1+2 fused, adjacency-last, y1 lives only in LDS.
// TT=8 output t's.  ybuf rows = (t - (t0-1))*17 + v, 170 rows x 72 pitch.
// Phases: stage xt | GEMM1 (B gathered from xt) -> z1 | mix1 in-place (y1)
//         | GEMM2 (B=ybuf) acc in regs + residual preload | z2 -> ybuf
//         | mix2 + residual + coalesced full-line y2 store.
// m-tile-per-wave: weight frags = 24 VGPR, each wave owns 16 o's.
// ---------------------------------------------------------------------------
__global__ __launch_bounds__(256, 4) void stgcn_ab_kernel(
    const float* __restrict__ x, const float* __restrict__ adj,
    const short* __restrict__ effT0, const short* __restrict__ effT12,
    const float* __restrict__ bnc, short* __restrict__ y2)
{
    __shared__ float adj_s[289];
    __shared__ __align__(16) float xt[12 * 51];        // 2448 B
    __shared__ __align__(16) short ybuf[170 * 72];     // 24480 B

    const int tid = threadIdx.x;
    const int b = blockIdx.y;
    const int t0 = blockIdx.x * 8;
    const int lane = tid & 63, wave = tid >> 6;
    const int col = lane & 15, kgrp = lane >> 4;

    for (int i = tid; i < 289; i += 256) adj_s[i] = adj[i];
    {
        const int tbase = t0 - 2;
        const float* xb = x + (size_t)(b * T_DIM + tbase) * 51;
        for (int i = tid; i < 612; i += 256) {
            int tt = tbase + i / 51;
            xt[i] = (tt >= 0 && tt < T_DIM) ? xb[i] : 0.f;
        }
    }
    // weight A-frags (m-tile per wave: o = wave*16 + col)
    s16x8 af1 = *(const s16x8*)(effT0 + (wave * 16 + col) * 32 + kgrp * 8);
    s16x8 af2[6];
    #pragma unroll
    for (int kk = 0; kk < 6; kk++)
        af2[kk] = *(const s16x8*)(effT12 +
            (wave * 16 + col) * 192 + kk * 32 + kgrp * 8);
    __syncthreads();

    // ---- GEMM1: 170 rows (11 tiles), K=32; B per-lane gathered from xt ----
    for (int tile = 0; tile < 11; tile++) {
        const int r = tile * 16 + col;
        const int me = r < 170 ? r : 169;
        const int s = (me * 241) >> 12;     // me/17
        const int k = me - s * 17;
        s16x8 bfr = (s16x8){0,0,0,0,0,0,0,0};
        if (kgrp < 3) {                      // dt = kgrp
            const float* xp = &xt[(s + kgrp) * 51 + k * 3];
            bfr[0] = f2bf_fast(xp[0]);
            bfr[1] = f2bf_fast(xp[1]);
            bfr[2] = f2bf_fast(xp[2]);
        }
        f32x4 acc = __builtin_amdgcn_mfma_f32_16x16x32_bf16(
            af1, bfr, (f32x4){0.f, 0.f, 0.f, 0.f}, 0, 0, 0);
        if (r < 170) {
            u32x2 st;
            st[0] = pk2bf(acc[0], acc[1]);
            st[1] = pk2bf(acc[2], acc[3]);
            *(u32x2*)&ybuf[r * 72 + wave * 16 + kgrp * 4] = st;
        }
    }
    __syncthreads();

    // ---- mix1 (in-place): y1 = relu(bn1(sum_k adj * z1)), zero OOB t ----
    for (int idx = tid; idx < 320; idx += 256) {
        const int tl = idx >> 5, oq = idx & 31, o0 = oq * 2;
        const int t = t0 - 1 + tl;
        const bool valid = (t >= 0) && (t < T_DIM);
        const float inv0 = bnc[o0], inv1 = bnc[o0 + 1];
        const float sh0 = bnc[192 + o0], sh1 = bnc[192 + o0 + 1];
        float zk0[17], zk1[17];
        #pragma unroll
        for (int k = 0; k < 17; k++) {
            unsigned u = *(const unsigned*)&ybuf[(tl * 17 + k) * 72 + o0];
            zk0[k] = bf2f((short)(u & 0xFFFF));
            zk1[k] = bf2f((short)(u >> 16));
        }
        #pragma unroll
        for (int v = 0; v < 17; v++) {
            float g0 = 0.f, g1 = 0.f;
            #pragma unroll
            for (int e = NBR_PTR[v]; e < NBR_PTR[v + 1]; e++) {
                int k = NBR_K[e];
                float w = adj_s[k * 17 + v];
                g0 += w * zk0[k]; g1 += w * zk1[k];
            }
            float v0 = valid ? fmaxf(g0 * inv0 + sh0, 0.f) : 0.f;
            float v1 = valid ? fmaxf(g1 * inv1 + sh1, 0.f) : 0.f;
            *(unsigned*)&ybuf[(tl * 17 + v) * 72 + o0] = pk2bf(v0, v1);
        }
    }
    __syncthreads();

    // ---- GEMM2: 136 rows (9 tiles), K=192, acc in regs ----
    f32x4 acc2[9];
    #pragma unroll
    for (int t2 = 0; t2 < 9; t2++) acc2[t2] = (f32x4){0.f, 0.f, 0.f, 0.f};
    #pragma unroll
    for (int kk = 0; kk < 6; kk++) {
        #pragma unroll
        for (int t2 = 0; t2 < 9; t2++) {
            const int r = t2 * 16 + col;
            const int me = r < 136 ? r : 135;
            s16x8 bfr = *(const s16x8*)&ybuf[
                (me + 17 * (kk >> 1)) * 72 + (kk & 1) * 32 + kgrp * 8];
            acc2[t2] = __builtin_amdgcn_mfma_f32_16x16x32_bf16(
                af2[kk], bfr, acc2[t2], 0, 0, 0);
        }
    }
    // residual preload (y1 rows 17..152) into regs before overwrite
    unsigned rv[17];
    {
        const int tl = tid >> 5, o0 = (tid & 31) * 2;
        #pragma unroll
        for (int v = 0; v < 17; v++)
            rv[v] = *(const unsigned*)&ybuf[((tl + 1) * 17 + v) * 72 + o0];
    }
    __syncthreads();

    // ---- z2 -> ybuf rows 0..135 ----
    #pragma unroll
    for (int t2 = 0; t2 < 9; t2++) {
        const int r = t2 * 16 + col;
        if (r < 136) {
            u32x2 st;
            st[0] = pk2bf(acc2[t2][0], acc2[t2][1]);
            st[1] = pk2bf(acc2[t2][2], acc2[t2][3]);
            *(u32x2*)&ybuf[r * 72 + wave * 16 + kgrp * 4] = st;
        }
    }
    __syncthreads();

    // ---- mix2 + residual + coalesced y2 store ----
    {
        const int tl = tid >> 5, o0 = (tid & 31) * 2;
        const float inv0 = bnc[64 + o0], inv1 = bnc[64 + o0 + 1];
        const float sh0 = bnc[256 + o0], sh1 = bnc[256 + o0 + 1];
        float zk0[17], zk1[17];
        #pragma unroll
        for (int k = 0; k < 17; k++) {
            unsigned u = *(const unsigned*)&ybuf[(tl * 17 + k) * 72 + o0];
            zk0[k] = bf2f((short)(u & 0xFFFF));
            zk1[k] = bf2f((short)(u >> 16));
        }
        const size_t gout = ((size_t)(b * T_DIM + t0 + tl) * K_DIM) * 64;
        #pragma unroll
        for (int v = 0; v < 17; v++) {
            float g0 = 0.f, g1 = 0.f;
            #pragma unroll
            for (int e = NBR_PTR[v]; e < NBR_PTR[v + 1]; e++) {
                int k = NBR_K[e];
                float w = adj_s[k * 17 + v];
                g0 += w * zk0[k]; g1 += w * zk1[k];
            }
            float v0 = fmaxf(g0 * inv0 + sh0, 0.f) + bf2f((short)(rv[v] & 0xFFFF));
            float v1 = fmaxf(g1 * inv1 + sh1, 0.f) + bf2f((short)(rv[v] >> 16));
            *(unsigned*)&y2[gout + (size_t)v * 64 + o0] = pk2bf(v0, v1);
        }
    }
}

// ---------------------------------------------------------------------------
// Kernel B: block 3 (DIL=2) + pool.  Coalesced-stage y2 tile (12 t x 17 k)
// into LDS; GEMM3 acc in regs; residual pre-summed to 2 regs; z3 overwrites
// stage after barrier; mix3 + pool -> part.
// ---------------------------------------------------------------------------
__global__ __launch_bounds__(256, 4) void stgcn_c_kernel(
    const short* __restrict__ y2, const float* __restrict__ adj,
    const short* __restrict__ effW3, const float* __restrict__ bnc,
    float* __restrict__ part, int b0)
{
    __shared__ float adj_s[289];
    __shared__ __align__(16) short ybuf[204 * 72];     // 29376 B
    __shared__ float pr[8][64];

    const int tid = threadIdx.x;
    const int b = blockIdx.y;
    const int t0 = blockIdx.x * 8;
    const int lane = tid & 63, wave = tid >> 6;
    const int col = lane & 15, kgrp = lane >> 4;

    for (int i = tid; i < 289; i += 256) adj_s[i] = adj[i];
    s16x8 af3[6];
    #pragma unroll
    for (int kk = 0; kk < 6; kk++)
        af3[kk] = *(const s16x8*)(effW3 +
            (wave * 16 + col) * 192 + kk * 32 + kgrp * 8);

    // coalesced stage: rows (t0-2 .. t0+9) x 17 k, zero-fill OOB
    {
        const int bLo = b * (T_DIM * 17);
        const int bHi = bLo + T_DIM * 17;
        const int g0r = bLo + (t0 - 2) * 17;
        for (int idx = tid; idx < 1632; idx += 256) {
            const int row = idx >> 3, c = idx & 7;
            const int gr = g0r + row;
            s16x8 v = (s16x8){0,0,0,0,0,0,0,0};
            if (gr >= bLo && gr < bHi)
                v = *(const s16x8*)(y2 + (size_t)gr * 64 + c * 8);
            *(s16x8*)&ybuf[row * 72 + c * 8] = v;
        }
    }
    __syncthreads();

    // ---- GEMM3: 136 rows (9 tiles), K=192, DIL=2, acc in regs ----
    f32x4 acc3[9];
    #pragma unroll
    for (int t3 = 0; t3 < 9; t3++) acc3[t3] = (f32x4){0.f, 0.f, 0.f, 0.f};
    #pragma unroll
    for (int kk = 0; kk < 6; kk++) {
        #pragma unroll
        for (int t3 = 0; t3 < 9; t3++) {
            const int r = t3 * 16 + col;
            const int me = r < 136 ? r : 135;
            s16x8 bfr = *(const s16x8*)&ybuf[
                (me + 34 * (kk >> 1)) * 72 + (kk & 1) * 32 + kgrp * 8];
            acc3[t3] = __builtin_amdgcn_mfma_f32_16x16x32_bf16(
                af3[kk], bfr, acc3[t3], 0, 0, 0);
        }
    }
    // residual pre-sum (rows 34..169 = y2[t0..t0+7]) -> 2 regs
    float rs0 = 0.f, rs1 = 0.f;
    {
        const int tl = tid >> 5, o0 = (tid & 31) * 2;
        #pragma unroll
        for (int v = 0; v < 17; v++) {
            unsigned u = *(const unsigned*)&ybuf[((tl + 2) * 17 + v) * 72 + o0];
            rs0 += bf2f((short)(u & 0xFFFF));
            rs1 += bf2f((short)(u >> 16));
        }
    }
    __syncthreads();

    // ---- z3 -> ybuf rows 0..135 ----
    #pragma unroll
    for (int t3 = 0; t3 < 9; t3++) {
        const int r = t3 * 16 + col;
        if (r < 136) {
            u32x2 st;
            st[0] = pk2bf(acc3[t3][0], acc3[t3][1]);
            st[1] = pk2bf(acc3[t3][2], acc3[t3][3]);
            *(u32x2*)&ybuf[r * 72 + wave * 16 + kgrp * 4] = st;
        }
    }
    __syncthreads();

    // ---- mix3 + pool ----
    {
        const int tl = tid >> 5, o0 = (tid & 31) * 2;
        const float inv0 = bnc[128 + o0], inv1 = bnc[128 + o0 + 1];
        const float sh0 = bnc[320 + o0], sh1 = bnc[320 + o0 + 1];
        float zk0[17], zk1[17];
        #pragma unroll
        for (int k = 0; k < 17; k++) {
            unsigned u = *(const unsigned*)&ybuf[(tl * 17 + k) * 72 + o0];
            zk0[k] = bf2f((short)(u & 0xFFFF));
            zk1[k] = bf2f((short)(u >> 16));
        }
        float ps0 = rs0, ps1 = rs1;
        #pragma unroll
        for (int v = 0; v < 17; v++) {
            float g0 = 0.f, g1 = 0.f;
            #pragma unroll
            for (int e = NBR_PTR[v]; e < NBR_PTR[v + 1]; e++) {
                int k = NBR_K[e];
                float w = adj_s[k * 17 + v];
                g0 += w * zk0[k]; g1 += w * zk1[k];
            }
            ps0 += fmaxf(g0 * inv0 + sh0, 0.f);
            ps1 += fmaxf(g1 * inv1 + sh1, 0.f);
        }
        *(float2*)&pr[tl][o0] = make_float2(ps0, ps1);
    }
    __syncthreads();
    if (tid < 64) {
        float s = 0.f;
        #pragma unroll
        for (int i = 0; i < 8; i++) s += pr[i][tid];
        part[((size_t)(b0 + b) * 256 + blockIdx.x) * 64 + tid] = s;
    }
}

// ---------------------------------------------------------------------------
// Sum 256 partials per (b,c), mean, LayerNorm, FC. 1 wave per b.
// ---------------------------------------------------------------------------
__global__ __launch_bounds__(64) void finish_kernel(
    const float* __restrict__ part, const float* __restrict__ ln_s,
    const float* __restrict__ ln_b, const float* __restrict__ fc_w,
    const float* __restrict__ fc_b, float* __restrict__ out)
{
    const int b = blockIdx.x;
    const int c = threadIdx.x;
    float s = 0.f;
    for (int i = 0; i < 256; i++)
        s += part[((size_t)b * 256 + i) * 64 + c];
    float feat = s / (float)(T_DIM * K_DIM);

    float m = feat;
    #pragma unroll
    for (int off = 32; off > 0; off >>= 1) m += __shfl_down(m, off);
    m = __shfl(m, 0) / 64.f;
    float d = feat - m;
    float v = d * d;
    #pragma unroll
    for (int off = 32; off > 0; off >>= 1) v += __shfl_down(v, off);
    v = __shfl(v, 0) / 64.f;
    float norm = d * rsqrtf(v + 1e-5f) * ln_s[c] + ln_b[c];

    __shared__ float ns[64];
    ns[c] = norm;
    __syncthreads();
    if (c < 10) {
        float o = fc_b[c];
        for (int i = 0; i < 64; i++) o += ns[i] * fc_w[i * 10 + c];
        out[b * 10 + c] = o;
    }
}

// ---------------------------------------------------------------------------
extern "C" void kernel_launch(void* const* d_in, const int* in_sizes, int n_in,
                              void* d_out, int out_size, void* d_ws, size_t ws_size,
                              hipStream_t stream)
{
    const float* kpts = (const float*)d_in[0];
    const float* adj  = (const float*)d_in[1];
    const float* gw0  = (const float*)d_in[2];
    const float* gw1  = (const float*)d_in[3];
    const float* gw2  = (const float*)d_in[4];
    const float* tcn  = (const float*)d_in[5];
    const float* bns  = (const float*)d_in[6];
    const float* bnb  = (const float*)d_in[7];
    const float* bnm  = (const float*)d_in[8];
    const float* bnv  = (const float*)d_in[9];
    const float* lns  = (const float*)d_in[10];
    const float* lnb  = (const float*)d_in[11];
    const float* fcw  = (const float*)d_in[12];
    const float* fcb  = (const float*)d_in[13];
    float* out = (float*)d_out;

    // ws: bnc(384 f) | part(32*256*64 f) | effT0(2048 s) | effT12(24576 s) | y2
    float* bnc  = (float*)d_ws;
    float* part = bnc + 384;
    short* effT0  = (short*)(part + (size_t)B_DIM * 256 * 64);
    short* effT12 = effT0 + 2048;
    short* y2     = effT12 + 24576;
    const size_t fixed_bytes = 384 * 4 + (size_t)B_DIM * 256 * 64 * 4
                             + 2048 * 2 + 24576 * 2;          // ~2.15 MB
    const size_t y_per_b = (size_t)T_DIM * K_DIM * 64 * 2;    // 4,456,448 B

    int cb = B_DIM;                 // single y2 buffer: cb=32 needs ~145 MB
    while (cb > 1 && fixed_bytes + (size_t)cb * y_per_b > ws_size) cb >>= 1;

    fold_weights_kernel<<<64, 256, 0, stream>>>(gw0, gw1, gw2, tcn,
                                                bns, bnb, bnm, bnv,
                                                effT0, effT12, bnc);

    for (int b0 = 0; b0 < B_DIM; b0 += cb) {
        stgcn_ab_kernel<<<dim3(T_DIM / 8, cb), 256, 0, stream>>>(
            kpts + (size_t)b0 * T_DIM * K_DIM * 3, adj, effT0, effT12, bnc, y2);
        stgcn_c_kernel<<<dim3(T_DIM / 8, cb), 256, 0, stream>>>(
            y2, adj, effT12 + 12288, bnc, part, b0);
    }

    finish_kernel<<<B_DIM, 64, 0, stream>>>(part, lns, lnb, fcw, fcb, out);
}